// Round 4
// baseline (689.390 us; speedup 1.0000x reference)
//
#include <hip/hip_runtime.h>
#include <hip/hip_bf16.h>

#define Bdim 256
#define Ddim 1024
#define Hdim 2048
#define Tdim 100
#define BH (Bdim*Hdim)            // 524288
#define M3 ((Tdim-1)*Bdim)        // 25344

#define OUT_MEM ((size_t)BH)                          // mem_rec starts after out0
#define OUT_SPK ((size_t)BH + (size_t)Tdim*2*BH)      // spk_rec after mem_rec

typedef __attribute__((ext_vector_type(8))) short short8;
typedef __attribute__((ext_vector_type(4))) float f32x4;

// async global->LDS, 16B per lane, LDS dest = wave-uniform base + lane*16
#define GLD16(g, l) __builtin_amdgcn_global_load_lds( \
    (__attribute__((address_space(1))) void*)(g), \
    (__attribute__((address_space(3))) void*)(l), 16, 0, 0)

// ---------------- K1: ns0 = X @ W0 (fp32, computed once) ----------------
__global__ __launch_bounds__(512) void k1_ns0(const float* __restrict__ X,
                                              const float* __restrict__ W0,
                                              float* __restrict__ NS0) {
  __shared__ float As[16][65];
  __shared__ float Bs[16][65];
  int tid = threadIdx.x;
  int tm = tid >> 4;      // 0..31 -> 2 rows each
  int tn = tid & 15;      // 0..15 -> 4 cols each
  int bm = blockIdx.x * 64, bn = blockIdx.y * 64;
  float acc[2][4] = {};
  for (int k0 = 0; k0 < Ddim; k0 += 16) {
    for (int i = tid; i < 64*16; i += 512) {
      int m = i >> 4, k = i & 15;
      As[k][m] = X[(size_t)(bm + m)*Ddim + k0 + k];
    }
    for (int i = tid; i < 16*64; i += 512) {
      int k = i >> 6, n = i & 63;
      Bs[k][n] = W0[(size_t)(k0 + k)*Hdim + bn + n];
    }
    __syncthreads();
    #pragma unroll
    for (int k = 0; k < 16; ++k) {
      float a0 = As[k][tm*2], a1 = As[k][tm*2+1];
      float b[4];
      #pragma unroll
      for (int j = 0; j < 4; ++j) b[j] = Bs[k][tn*4+j];
      #pragma unroll
      for (int j = 0; j < 4; ++j) {
        acc[0][j] = fmaf(a0, b[j], acc[0][j]);
        acc[1][j] = fmaf(a1, b[j], acc[1][j]);
      }
    }
    __syncthreads();
  }
  for (int i = 0; i < 2; ++i)
    for (int j = 0; j < 4; ++j)
      NS0[(size_t)(bm + tm*2 + i)*Hdim + bn + tn*4 + j] = acc[i][j];
}

// ---------------- K2b: W1T[n][k] = bf16(W1[k][n]) ----------------
__global__ __launch_bounds__(256) void k2b_tr(const float* __restrict__ W1,
                                              unsigned short* __restrict__ W1T) {
  __shared__ unsigned short tile[32][33];
  int bk = blockIdx.x*32, bn = blockIdx.y*32;
  int tx = threadIdx.x & 31, ty = threadIdx.x >> 5;
  for (int r = ty; r < 32; r += 8) {
    float f = W1[(size_t)(bk + r)*Hdim + bn + tx];
    __hip_bfloat16 h = __float2bfloat16(f);
    tile[r][tx] = *reinterpret_cast<unsigned short*>(&h);
  }
  __syncthreads();
  for (int r = ty; r < 32; r += 8) {
    W1T[(size_t)(bn + r)*Hdim + bk + tx] = tile[tx][r];
  }
}

// ---------------- K2: layer-0 sim; writes mem0_rec, spk_rec, t=0 zeros, bf16 Z ----------------
__global__ __launch_bounds__(256) void k2_sim(const float* __restrict__ NS0,
                                              float* __restrict__ out,
                                              unsigned short* __restrict__ Zb) {
  size_t idx = (size_t)blockIdx.x*256 + threadIdx.x;  // b*H + j
  float ns = NS0[idx];
  float* mem = out + OUT_MEM;
  float* spk = out + OUT_SPK;
  mem[idx] = 0.f;          // mem_rec[0][0]
  mem[BH + idx] = 0.f;     // mem_rec[0][1]
  spk[idx] = 0.f;          // spk_rec[0]
  float m = 0.f;
  for (int t = 1; t < Tdim; ++t) {
    m = __fadd_rn(__fmul_rn(0.9f, m), ns);   // match numpy's mul-then-add rounding
    bool sp = m > 1.0f;                       // mthr > 0
    float z = sp ? 1.f : 0.f;
    if (sp) m = 0.f;                          // reset, recorded post-reset
    mem[(size_t)(2*t)*BH + idx] = m;
    spk[(size_t)t*BH + idx] = z;
    Zb[(size_t)(t-1)*BH + idx] = sp ? (unsigned short)0x3F80 : (unsigned short)0;
  }
}

// ---------------- K3: C[25344,2048] = Z @ W1, fp32 C planes into mem_rec[t][1] ----------------
// 256x256 tile, BK=32, 8 waves (2Mx4N), 3 LDS buffers, counted vmcnt(4) pipeline (T3+T4),
// setprio around MFMA cluster (T5), T2 source-preswizzle (round-3-validated involution),
// XCD-bijective grid swizzle, ntile-fast (T1). One barrier + one counted vmcnt per K-tile.
#define K3_BK 32
#define NKT (Hdim/K3_BK)   // 64 K-tiles

__global__ __launch_bounds__(512) void k3_gemm(const unsigned short* __restrict__ A,   // Zb [M3][2048]
                                               const unsigned short* __restrict__ BT,  // W1T [2048][2048]
                                               float* __restrict__ mem1) {             // out + OUT_MEM
  __shared__ short As[3][256*K3_BK];  // 3 x 16 KB
  __shared__ short Bs[3][256*K3_BK];  // 3 x 16 KB   (96 KB total)
  int tid = threadIdx.x;
  int l = tid & 63;
  int w = tid >> 6;                 // wave 0..7
  int wm = w >> 2, wn = w & 3;      // 2 x 4 wave grid; per-wave out = 128 x 64
  int lr = l & 15, lg = l >> 4;

  // T1: grid 792 = 8 * 99, bijective; ntile fast within an XCD chunk -> A-panel L2 reuse
  int lin = blockIdx.x;
  int wg = (lin & 7)*99 + (lin >> 3);
  int mtile = wg >> 3, ntile = wg & 7;
  size_t gm = (size_t)mtile * 256;
  size_t gn = (size_t)ntile * 256;

  // staging: half h = 128 rows; wave w owns rows h*128 + w*16 .. +15 (1 KB chunk)
  // T2 rule-21: LDS linear, global source col pre-swizzled with the read-side involution.
  int srow = l >> 2;
  int scol = ((l & 3)*8) ^ (((l >> 2) & 6) << 2);
  const unsigned short* ga0 = &A [(gm +       w*16 + srow)*Hdim + scol];
  const unsigned short* ga1 = &A [(gm + 128 + w*16 + srow)*Hdim + scol];
  const unsigned short* gb0 = &BT[(gn +       w*16 + srow)*Hdim + scol];
  const unsigned short* gb1 = &BT[(gn + 128 + w*16 + srow)*Hdim + scol];
  int lo0 = w*512;           // shorts: half0 chunk base
  int lo1 = 4096 + w*512;    // half1

  #define K3_STAGE(buf, kt) do { size_t ko = (size_t)(kt)*K3_BK;   \
      GLD16(ga0 + ko, &As[buf][lo0]);                               \
      GLD16(ga1 + ko, &As[buf][lo1]);                               \
      GLD16(gb0 + ko, &Bs[buf][lo0]);                               \
      GLD16(gb1 + ko, &Bs[buf][lo1]); } while (0)

  f32x4 acc[8][4] = {};
  int rdswz = (lr & 6) << 2;   // read-side XOR (shorts)

  K3_STAGE(0, 0);
  K3_STAGE(1, 1);

  int cur = 0;
  for (int kt = 0; kt < NKT - 1; ++kt) {
    // buf[cur]'s 4 loads are the oldest outstanding; kt+1's 4 stay in flight (T4: never 0)
    asm volatile("s_waitcnt vmcnt(4)" ::: "memory");
    __builtin_amdgcn_s_barrier();
    __builtin_amdgcn_sched_barrier(0);
    int nxt2 = cur + 2; if (nxt2 >= 3) nxt2 -= 3;
    if (kt + 2 < NKT) K3_STAGE(nxt2, kt + 2);   // overwrites buf consumed at kt-1: safe past barrier kt
    short8 af[8], bf[4];
    #pragma unroll
    for (int mi = 0; mi < 8; ++mi)
      af[mi] = *reinterpret_cast<const short8*>(&As[cur][(wm*128 + mi*16 + lr)*K3_BK + (lg*8 ^ rdswz)]);
    #pragma unroll
    for (int ni = 0; ni < 4; ++ni)
      bf[ni] = *reinterpret_cast<const short8*>(&Bs[cur][(wn*64 + ni*16 + lr)*K3_BK + (lg*8 ^ rdswz)]);
    __builtin_amdgcn_s_setprio(1);
    #pragma unroll
    for (int mi = 0; mi < 8; ++mi)
      #pragma unroll
      for (int ni = 0; ni < 4; ++ni)
        acc[mi][ni] = __builtin_amdgcn_mfma_f32_16x16x32_bf16(af[mi], bf[ni], acc[mi][ni], 0, 0, 0);
    __builtin_amdgcn_s_setprio(0);
    ++cur; if (cur >= 3) cur -= 3;
  }
  // last K-tile: only its own 4 loads outstanding -> full drain once (epilogue)
  {
    asm volatile("s_waitcnt vmcnt(0)" ::: "memory");
    __builtin_amdgcn_s_barrier();
    __builtin_amdgcn_sched_barrier(0);
    short8 af[8], bf[4];
    #pragma unroll
    for (int mi = 0; mi < 8; ++mi)
      af[mi] = *reinterpret_cast<const short8*>(&As[cur][(wm*128 + mi*16 + lr)*K3_BK + (lg*8 ^ rdswz)]);
    #pragma unroll
    for (int ni = 0; ni < 4; ++ni)
      bf[ni] = *reinterpret_cast<const short8*>(&Bs[cur][(wn*64 + ni*16 + lr)*K3_BK + (lg*8 ^ rdswz)]);
    __builtin_amdgcn_s_setprio(1);
    #pragma unroll
    for (int mi = 0; mi < 8; ++mi)
      #pragma unroll
      for (int ni = 0; ni < 4; ++ni)
        acc[mi][ni] = __builtin_amdgcn_mfma_f32_16x16x32_bf16(af[mi], bf[ni], acc[mi][ni], 0, 0, 0);
    __builtin_amdgcn_s_setprio(0);
  }

  // epilogue: this M-tile == C plane t = mtile+1 -> contiguous [256][2048] fp32 plane
  // C/D layout: col = lane&15, row = (lane>>4)*4 + q (validated rounds 1-3)
  float* plane = mem1 + (size_t)(2*mtile + 3)*BH + gn;
  #pragma unroll
  for (int mi = 0; mi < 8; ++mi)
    #pragma unroll
    for (int ni = 0; ni < 4; ++ni)
      #pragma unroll
      for (int q = 0; q < 4; ++q) {
        int b   = wm*128 + mi*16 + lg*4 + q;
        int col = wn*64  + ni*16 + lr;
        plane[(size_t)b*Hdim + col] = acc[mi][ni][q];
      }
  #undef K3_STAGE
}

// ---------------- K4: in-place temporal recurrence over C planes -> mem1_rec + out0 ----------------
__global__ __launch_bounds__(256) void k4_rec(float* __restrict__ out) {
  size_t idx = (size_t)blockIdx.x*256 + threadIdx.x;  // b*H + j
  float* mem = out + OUT_MEM;
  float s = 0.f, m = 0.f;
  for (int t = 1; t < Tdim; ++t) {
    float* p = &mem[(size_t)(2*t + 1)*BH + idx];
    float c = *p;                           // C[t-1][b][j] (fp32, exact from MFMA)
    s = __fadd_rn(__fmul_rn(0.95f, s), c);
    m = __fadd_rn(__fmul_rn(0.9f, m), s);
    *p = m;                                 // mem_rec[t][1]
  }
  out[idx] = m;                             // mem1_rec[-1]
}

extern "C" void kernel_launch(void* const* d_in, const int* in_sizes, int n_in,
                              void* d_out, int out_size, void* d_ws, size_t ws_size,
                              hipStream_t stream) {
  const float* X  = (const float*)d_in[0];
  const float* W0 = (const float*)d_in[1];
  const float* W1 = (const float*)d_in[2];
  float* out = (float*)d_out;
  char* ws = (char*)d_ws;

  float*          ns0 = (float*)ws;                                   // 2 MiB
  unsigned short* w1t = (unsigned short*)(ws + (2ull  << 20));        // 8 MiB
  unsigned short* zb  = (unsigned short*)(ws + (10ull << 20));        // 99 MiB (fits, verified round 1)

  k1_ns0<<<dim3(Bdim/64, Hdim/64), 512, 0, stream>>>(X, W0, ns0);
  k2b_tr<<<dim3(Hdim/32, Hdim/32), 256, 0, stream>>>(W1, w1t);
  k2_sim<<<dim3(BH/256), 256, 0, stream>>>(ns0, out, zb);
  k3_gemm<<<dim3((M3/256)*(Hdim/256)), 512, 0, stream>>>(zb, w1t, out + OUT_MEM);
  k4_rec<<<dim3(BH/256), 256, 0, stream>>>(out);
}

// Round 6
// 526.150 us; speedup vs baseline: 1.3103x; 1.3103x over previous
//
#include <hip/hip_runtime.h>
#include <hip/hip_bf16.h>

#define Bdim 256
#define Ddim 1024
#define Hdim 2048
#define Tdim 100
#define BH (Bdim*Hdim)            // 524288
#define M3 ((Tdim-1)*Bdim)        // 25344

#define OUT_MEM ((size_t)BH)                          // mem_rec starts after out0
#define OUT_SPK ((size_t)BH + (size_t)Tdim*2*BH)      // spk_rec after mem_rec

typedef __attribute__((ext_vector_type(8))) short short8;
typedef __attribute__((ext_vector_type(4))) float f32x4;

// async global->LDS, 16B per lane, LDS dest = wave-uniform base + lane*16
#define GLD16(g, l) __builtin_amdgcn_global_load_lds( \
    (__attribute__((address_space(1))) void*)(g), \
    (__attribute__((address_space(3))) void*)(l), 16, 0, 0)

#define BAR() do { __builtin_amdgcn_sched_barrier(0); __builtin_amdgcn_s_barrier(); \
                   asm volatile("" ::: "memory"); __builtin_amdgcn_sched_barrier(0); } while(0)
#define LGKM0() do { asm volatile("s_waitcnt lgkmcnt(0)" ::: "memory"); \
                     __builtin_amdgcn_sched_barrier(0); } while(0)

static __device__ __forceinline__ unsigned short bf16bits(float f) {
  __hip_bfloat16 h = __float2bfloat16(f);
  return *reinterpret_cast<unsigned short*>(&h);
}

// ---------------- kcvt_split: X f32 -> bf16 hi + bf16 lo(residual) ----------------
__global__ __launch_bounds__(256) void kcvt_split(const float* __restrict__ X,
                                                  unsigned short* __restrict__ Xhi,
                                                  unsigned short* __restrict__ Xlo) {
  int i = (blockIdx.x*256 + threadIdx.x)*4;
  float4 v = *reinterpret_cast<const float4*>(&X[i]);
  ushort4 ph, pl;
  float f, fh;
  f = v.x; { __hip_bfloat16 h = __float2bfloat16(f); fh = __bfloat162float(h); ph.x = *reinterpret_cast<unsigned short*>(&h); } pl.x = bf16bits(f - fh);
  f = v.y; { __hip_bfloat16 h = __float2bfloat16(f); fh = __bfloat162float(h); ph.y = *reinterpret_cast<unsigned short*>(&h); } pl.y = bf16bits(f - fh);
  f = v.z; { __hip_bfloat16 h = __float2bfloat16(f); fh = __bfloat162float(h); ph.z = *reinterpret_cast<unsigned short*>(&h); } pl.z = bf16bits(f - fh);
  f = v.w; { __hip_bfloat16 h = __float2bfloat16(f); fh = __bfloat162float(h); ph.w = *reinterpret_cast<unsigned short*>(&h); } pl.w = bf16bits(f - fh);
  *reinterpret_cast<ushort4*>(&Xhi[i]) = ph;
  *reinterpret_cast<ushort4*>(&Xlo[i]) = pl;
}

// ---------------- ktr_bf16: Out[C][R] = bf16(In[R][C]^T) ----------------
__global__ __launch_bounds__(256) void ktr_bf16(const float* __restrict__ In,
                                                unsigned short* __restrict__ Out,
                                                int R, int C) {
  __shared__ unsigned short tile[32][33];
  int bk = blockIdx.x*32, bn = blockIdx.y*32;
  int tx = threadIdx.x & 31, ty = threadIdx.x >> 5;
  for (int r = ty; r < 32; r += 8)
    tile[r][tx] = bf16bits(In[(size_t)(bk + r)*C + bn + tx]);
  __syncthreads();
  for (int r = ty; r < 32; r += 8)
    Out[(size_t)(bn + r)*R + bk + tx] = tile[tx][r];
}

// ---------------- ktr_split: transposed hi/lo split of In (f32) ----------------
__global__ __launch_bounds__(256) void ktr_split(const float* __restrict__ In,
                                                 unsigned short* __restrict__ OutHi,
                                                 unsigned short* __restrict__ OutLo,
                                                 int R, int C) {
  __shared__ unsigned short thi[32][33];
  __shared__ unsigned short tlo[32][33];
  int bk = blockIdx.x*32, bn = blockIdx.y*32;
  int tx = threadIdx.x & 31, ty = threadIdx.x >> 5;
  for (int r = ty; r < 32; r += 8) {
    float f = In[(size_t)(bk + r)*C + bn + tx];
    __hip_bfloat16 h = __float2bfloat16(f);
    float fh = __bfloat162float(h);
    thi[r][tx] = *reinterpret_cast<unsigned short*>(&h);
    tlo[r][tx] = bf16bits(f - fh);
  }
  __syncthreads();
  for (int r = ty; r < 32; r += 8) {
    OutHi[(size_t)(bn + r)*R + bk + tx] = thi[tx][r];
    OutLo[(size_t)(bn + r)*R + bk + tx] = tlo[tx][r];
  }
}

// ---------------- K1: ns0 (+)= A @ BT (bf16 MFMA, round-3-validated 2-phase 128^2) ----------------
#define K1BK 32
#define K1NK 32   // K=1024
template<int ACC>
__global__ __launch_bounds__(256) void k1_mfma(const unsigned short* __restrict__ A,   // [256][1024]
                                               const unsigned short* __restrict__ BT,  // [2048][1024]
                                               float* __restrict__ NS0) {              // [256][2048]
  __shared__ short As[2][128*K1BK];
  __shared__ short Bs[2][128*K1BK];
  int tid = threadIdx.x;
  int l = tid & 63, w = tid >> 6;
  int wr = (w >> 1) << 6, wc = (w & 1) << 6;
  int lr = l & 15, lg = l >> 4;
  size_t gm = (size_t)blockIdx.x * 128;
  size_t gn = (size_t)blockIdx.y * 128;
  int c0 = w*2, c1 = w*2 + 1;
  int srow = l >> 2;
  int scol = ((l & 3)*8) ^ (((l >> 2) & 6) << 2);
  const unsigned short* a0 = &A [(gm + c0*16 + srow)*1024 + scol];
  const unsigned short* a1 = &A [(gm + c1*16 + srow)*1024 + scol];
  const unsigned short* b0 = &BT[(gn + c0*16 + srow)*1024 + scol];
  const unsigned short* b1 = &BT[(gn + c1*16 + srow)*1024 + scol];
  int rdswz = (lr & 6) << 2;
  f32x4 acc[4][4] = {};
  GLD16(a0, &As[0][c0*512]); GLD16(a1, &As[0][c1*512]);
  GLD16(b0, &Bs[0][c0*512]); GLD16(b1, &Bs[0][c1*512]);
  __syncthreads();
  #pragma unroll 2
  for (int t = 0; t < K1NK; ++t) {
    int cur = t & 1;
    if (t + 1 < K1NK) {
      int nxt = cur ^ 1; size_t ko = (size_t)(t + 1)*K1BK;
      GLD16(a0 + ko, &As[nxt][c0*512]); GLD16(a1 + ko, &As[nxt][c1*512]);
      GLD16(b0 + ko, &Bs[nxt][c0*512]); GLD16(b1 + ko, &Bs[nxt][c1*512]);
    }
    short8 af[4], bfr[4];
    #pragma unroll
    for (int mi = 0; mi < 4; ++mi)
      af[mi] = *reinterpret_cast<const short8*>(&As[cur][(wr + mi*16 + lr)*K1BK + (lg*8 ^ rdswz)]);
    #pragma unroll
    for (int ni = 0; ni < 4; ++ni)
      bfr[ni] = *reinterpret_cast<const short8*>(&Bs[cur][(wc + ni*16 + lr)*K1BK + (lg*8 ^ rdswz)]);
    #pragma unroll
    for (int mi = 0; mi < 4; ++mi)
      #pragma unroll
      for (int ni = 0; ni < 4; ++ni)
        acc[mi][ni] = __builtin_amdgcn_mfma_f32_16x16x32_bf16(af[mi], bfr[ni], acc[mi][ni], 0, 0, 0);
    __syncthreads();
  }
  #pragma unroll
  for (int mi = 0; mi < 4; ++mi)
    #pragma unroll
    for (int ni = 0; ni < 4; ++ni)
      #pragma unroll
      for (int q = 0; q < 4; ++q) {
        size_t o = (gm + wr + mi*16 + lg*4 + q)*Hdim + gn + wc + ni*16 + lr;
        if (ACC) NS0[o] = __fadd_rn(NS0[o], acc[mi][ni][q]);
        else     NS0[o] = acc[mi][ni][q];
      }
}

// ---------------- K2: layer-0 sim; writes mem0_rec, spk_rec, t=0 zeros, bf16 Z ----------------
__global__ __launch_bounds__(256) void k2_sim(const float* __restrict__ NS0,
                                              float* __restrict__ out,
                                              unsigned short* __restrict__ Zb) {
  size_t idx = (size_t)blockIdx.x*256 + threadIdx.x;  // b*H + j
  float ns = NS0[idx];
  float* mem = out + OUT_MEM;
  float* spk = out + OUT_SPK;
  mem[idx] = 0.f;
  mem[BH + idx] = 0.f;
  spk[idx] = 0.f;
  float m = 0.f;
  for (int t = 1; t < Tdim; ++t) {
    m = __fadd_rn(__fmul_rn(0.9f, m), ns);
    bool sp = m > 1.0f;
    float z = sp ? 1.f : 0.f;
    if (sp) m = 0.f;
    mem[(size_t)(2*t)*BH + idx] = m;
    spk[(size_t)t*BH + idx] = z;
    Zb[(size_t)(t-1)*BH + idx] = sp ? (unsigned short)0x3F80 : (unsigned short)0;
  }
}

// ---------------- K3: C = Z @ W1, 256^2 tile, BK=64, 8-wave, 4-phase/K-tile counted-vmcnt pipeline ----
#define NKT3 32   // 2048/64

#define K3_ST(g, ldsarr, half, kt) do { \
  int _b = (kt) & 1; \
  const unsigned short* _p = (g) + (size_t)(kt)*64 + (size_t)(half)*128*Hdim; \
  GLD16(_p,          &ldsarr[_b][(half)*8192 + w*1024]); \
  GLD16(_p + 8*Hdim, &ldsarr[_b][(half)*8192 + w*1024 + 512]); \
} while(0)

#define K3_LDA(h) do { \
  _Pragma("unroll") \
  for (int mi = 0; mi < 4; ++mi) \
    _Pragma("unroll") \
    for (int ks = 0; ks < 2; ++ks) \
      af[mi][ks] = *reinterpret_cast<const short8*>(&As[bb][((h)*128 + wm*64 + mi*16 + lr)*64 + ((ks*32 + lg*8) ^ rs)]); \
} while(0)

#define K3_LDB(v, bf) do { \
  _Pragma("unroll") \
  for (int ni = 0; ni < 2; ++ni) \
    _Pragma("unroll") \
    for (int ks = 0; ks < 2; ++ks) \
      bf[ni][ks] = *reinterpret_cast<const short8*>(&Bs[bb][((v)*128 + wn*32 + ni*16 + lr)*64 + ((ks*32 + lg*8) ^ rs)]); \
} while(0)

#define K3_MFMA(h, v, bf) do { \
  __builtin_amdgcn_s_setprio(1); \
  _Pragma("unroll") \
  for (int ks = 0; ks < 2; ++ks) \
    _Pragma("unroll") \
    for (int mi = 0; mi < 4; ++mi) \
      _Pragma("unroll") \
      for (int ni = 0; ni < 2; ++ni) \
        acc[(h)*4+mi][(v)*2+ni] = __builtin_amdgcn_mfma_f32_16x16x32_bf16(af[mi][ks], bf[ni][ks], acc[(h)*4+mi][(v)*2+ni], 0, 0, 0); \
  __builtin_amdgcn_s_setprio(0); \
} while(0)

__global__ __launch_bounds__(512, 2) void k3_gemm(const unsigned short* __restrict__ A,   // Zb [M3][2048]
                                                  const unsigned short* __restrict__ BT,  // W1T [2048][2048]
                                                  float* __restrict__ mem1) {             // out + OUT_MEM
  __shared__ short As[2][256*64];   // 64 KB
  __shared__ short Bs[2][256*64];   // 64 KB
  int tid = threadIdx.x;
  int l = tid & 63;
  int w = tid >> 6;                 // wave 0..7
  int wm = w >> 2, wn = w & 3;      // 2M x 4N
  int lr = l & 15, lg = l >> 4;
  int rs = (lr & 7) << 3;           // read-side XOR, shorts (16B-slot granularity)

  // T1: grid 792 = 8*99 bijective, ntile fast
  int lin = blockIdx.x;
  int wg = (lin & 7)*99 + (lin >> 3);
  int mtile = wg >> 3, ntile = wg & 7;
  size_t gm = (size_t)mtile * 256;
  size_t gn = (size_t)ntile * 256;

  // staging: rule-21 pre-swizzled global source, linear LDS dest (row=l>>3, slot=l&7)
  int srow8 = l >> 3, sslot = l & 7;
  int scol3 = (sslot ^ srow8) << 3;
  const unsigned short* gA = &A [(gm + w*16 + srow8)*Hdim + scol3];
  const unsigned short* gB = &BT[(gn + w*16 + srow8)*Hdim + scol3];

  f32x4 acc[8][4] = {};

  // prologue: tile0 (4 half-tiles) + A-lo(1), B-hi(1)  -> 12 outstanding loads
  K3_ST(gA, As, 0, 0); K3_ST(gB, Bs, 0, 0);
  K3_ST(gA, As, 1, 0); K3_ST(gB, Bs, 1, 0);
  K3_ST(gA, As, 0, 1); K3_ST(gB, Bs, 1, 1);

  for (int kt = 0; kt < NKT3; ++kt) {
    int bb = kt & 1;
    // entry: tile kt's 4 half-tiles are the 8 oldest outstanding -> counted wait (T4)
    if (kt == NKT3 - 1) asm volatile("s_waitcnt vmcnt(0)" ::: "memory");
    else                asm volatile("s_waitcnt vmcnt(4)" ::: "memory");
    __builtin_amdgcn_s_barrier();
    asm volatile("" ::: "memory");
    __builtin_amdgcn_sched_barrier(0);

    short8 af[4][2], bfl[2][2], bfh[2][2];

    // P1 (h0,v0): A-lo last LDS-read here; stage A-hi(kt+1) (region idle since kt-1.p3)
    K3_LDA(0); K3_LDB(0, bfl);
    if (kt + 1 < NKT3) K3_ST(gA, As, 1, kt + 1);
    BAR(); LGKM0();
    K3_MFMA(0, 0, bfl);
    BAR();
    // P2 (h0,v1): B-hi read; stage B-lo(kt+1) (idle since kt-1.p1)
    K3_LDB(1, bfh);
    if (kt + 1 < NKT3) K3_ST(gB, Bs, 0, kt + 1);
    BAR(); LGKM0();
    K3_MFMA(0, 1, bfh);
    BAR();
    // P3 (h1,v1): A-hi read; stage A-lo(kt+2) (A-lo reads finished >=2 barriers ago)
    K3_LDA(1);
    if (kt + 2 < NKT3) K3_ST(gA, As, 0, kt + 2);
    BAR(); LGKM0();
    K3_MFMA(1, 1, bfh);
    BAR();
    // P4 (h1,v0): no reads (bfl reused); stage B-hi(kt+2) (B-hi reads finished >=2 barriers ago)
    if (kt + 2 < NKT3) K3_ST(gB, Bs, 1, kt + 2);
    K3_MFMA(1, 0, bfl);
    // group-end barrier == next iteration's entry barrier
  }

  // epilogue: M-tile == C plane t = mtile+1; rows h*128 + wm*64 + mi*16, cols v*128 + wn*32 + ni*16
  float* plane = mem1 + (size_t)(2*mtile + 3)*BH + gn;
  #pragma unroll
  for (int hh = 0; hh < 2; ++hh)
    #pragma unroll
    for (int mi = 0; mi < 4; ++mi)
      #pragma unroll
      for (int vv = 0; vv < 2; ++vv)
        #pragma unroll
        for (int ni = 0; ni < 2; ++ni)
          #pragma unroll
          for (int q = 0; q < 4; ++q) {
            int b   = hh*128 + wm*64 + mi*16 + lg*4 + q;
            int col = vv*128 + wn*32 + ni*16 + lr;
            plane[(size_t)b*Hdim + col] = acc[hh*4+mi][vv*2+ni][q];
          }
}

// ---------------- K4: in-place temporal recurrence over C planes -> mem1_rec + out0 ----------------
__global__ __launch_bounds__(256) void k4_rec(float* __restrict__ out) {
  size_t idx = (size_t)blockIdx.x*256 + threadIdx.x;
  float* mem = out + OUT_MEM;
  float s = 0.f, m = 0.f;
  for (int t = 1; t < Tdim; ++t) {
    float* p = &mem[(size_t)(2*t + 1)*BH + idx];
    float c = *p;
    s = __fadd_rn(__fmul_rn(0.95f, s), c);
    m = __fadd_rn(__fmul_rn(0.9f, m), s);
    *p = m;
  }
  out[idx] = m;
}

extern "C" void kernel_launch(void* const* d_in, const int* in_sizes, int n_in,
                              void* d_out, int out_size, void* d_ws, size_t ws_size,
                              hipStream_t stream) {
  const float* X  = (const float*)d_in[0];
  const float* W0 = (const float*)d_in[1];
  const float* W1 = (const float*)d_in[2];
  float* out = (float*)d_out;
  char* ws = (char*)d_ws;

  float*          ns0 = (float*)ws;                                   // 2 MiB @0
  unsigned short* w1t = (unsigned short*)(ws + (2ull  << 20));        // 8 MiB @2M
  unsigned short* zb  = (unsigned short*)(ws + (10ull << 20));        // 99 MiB @10M (fits; verified rounds 2-4)
  // hi/lo split inputs live INSIDE the zb region; consumed by k1 before k2 overwrites with Zb
  unsigned short* xhi = (unsigned short*)(ws + (10ull << 20));              // 0.5 MiB
  unsigned short* xlo = (unsigned short*)(ws + (10ull << 20) + (512<<10));  // 0.5 MiB
  unsigned short* whi = (unsigned short*)(ws + (11ull << 20));              // 4 MiB
  unsigned short* wlo = (unsigned short*)(ws + (15ull << 20));              // 4 MiB

  kcvt_split<<<dim3(256),     256, 0, stream>>>(X, xhi, xlo);
  ktr_split <<<dim3(32, 64),  256, 0, stream>>>(W0, whi, wlo, 1024, 2048);  // W0T hi/lo [2048][1024]
  ktr_bf16  <<<dim3(64, 64),  256, 0, stream>>>(W1, w1t, 2048, 2048);       // W1T [2048][2048]
  // ns0 = xhi@whi + xhi@wlo + xlo@whi  (fp32 accumulate, fixed order -> deterministic)
  k1_mfma<0><<<dim3(2, 16),   256, 0, stream>>>(xhi, whi, ns0);
  k1_mfma<1><<<dim3(2, 16),   256, 0, stream>>>(xhi, wlo, ns0);
  k1_mfma<1><<<dim3(2, 16),   256, 0, stream>>>(xlo, whi, ns0);
  k2_sim <<<dim3(BH/256),     256, 0, stream>>>(ns0, out, zb);
  k3_gemm<<<dim3((M3/256)*(Hdim/256)), 512, 0, stream>>>(zb, w1t, out + OUT_MEM);
  k4_rec <<<dim3(BH/256),     256, 0, stream>>>(out);
}

// Round 7
// 488.545 us; speedup vs baseline: 1.4111x; 1.0770x over previous
//
#include <hip/hip_runtime.h>
#include <hip/hip_bf16.h>

#define Bdim 256
#define Ddim 1024
#define Hdim 2048
#define Tdim 100
#define BH (Bdim*Hdim)            // 524288
#define M3 ((Tdim-1)*Bdim)        // 25344
#define ZBYTES ((size_t)M3*Hdim*2)   // 103,809,024 B

#define OUT_MEM ((size_t)BH)                          // mem_rec starts after out0
#define OUT_SPK ((size_t)BH + (size_t)Tdim*2*BH)      // spk_rec after mem_rec

typedef __attribute__((ext_vector_type(8))) short short8;
typedef __attribute__((ext_vector_type(4))) float f32x4;

// async global->LDS, 16B per lane, LDS dest = wave-uniform base + lane*16
#define GLD16(g, l) __builtin_amdgcn_global_load_lds( \
    (__attribute__((address_space(1))) void*)(g), \
    (__attribute__((address_space(3))) void*)(l), 16, 0, 0)

// Lightweight barrier: compiler memory fences order LDS/global ops across the
// barrier (race safety) WITHOUT sched_barrier(0) order-pinning (m141 lesson).
#define BARL() do { asm volatile("" ::: "memory"); __builtin_amdgcn_s_barrier(); \
                    asm volatile("" ::: "memory"); } while(0)
// rule-18: sched_barrier(0) after lgkmcnt(0) so MFMA can't hoist above the wait
#define LGKM0() do { asm volatile("s_waitcnt lgkmcnt(0)" ::: "memory"); \
                     __builtin_amdgcn_sched_barrier(0); } while(0)

static __device__ __forceinline__ unsigned short bf16bits(float f) {
  __hip_bfloat16 h = __float2bfloat16(f);
  return *reinterpret_cast<unsigned short*>(&h);
}

// ---------------- kcvt_split: X f32 -> bf16 hi + bf16 lo(residual) ----------------
__global__ __launch_bounds__(256) void kcvt_split(const float* __restrict__ X,
                                                  unsigned short* __restrict__ Xhi,
                                                  unsigned short* __restrict__ Xlo) {
  int i = (blockIdx.x*256 + threadIdx.x)*4;
  float4 v = *reinterpret_cast<const float4*>(&X[i]);
  ushort4 ph, pl;
  float f, fh;
  f = v.x; { __hip_bfloat16 h = __float2bfloat16(f); fh = __bfloat162float(h); ph.x = *reinterpret_cast<unsigned short*>(&h); } pl.x = bf16bits(f - fh);
  f = v.y; { __hip_bfloat16 h = __float2bfloat16(f); fh = __bfloat162float(h); ph.y = *reinterpret_cast<unsigned short*>(&h); } pl.y = bf16bits(f - fh);
  f = v.z; { __hip_bfloat16 h = __float2bfloat16(f); fh = __bfloat162float(h); ph.z = *reinterpret_cast<unsigned short*>(&h); } pl.z = bf16bits(f - fh);
  f = v.w; { __hip_bfloat16 h = __float2bfloat16(f); fh = __bfloat162float(h); ph.w = *reinterpret_cast<unsigned short*>(&h); } pl.w = bf16bits(f - fh);
  *reinterpret_cast<ushort4*>(&Xhi[i]) = ph;
  *reinterpret_cast<ushort4*>(&Xlo[i]) = pl;
}

// ---------------- ktr_bf16: Out[C][R] = bf16(In[R][C]^T) ----------------
__global__ __launch_bounds__(256) void ktr_bf16(const float* __restrict__ In,
                                                unsigned short* __restrict__ Out,
                                                int R, int C) {
  __shared__ unsigned short tile[32][33];
  int bk = blockIdx.x*32, bn = blockIdx.y*32;
  int tx = threadIdx.x & 31, ty = threadIdx.x >> 5;
  for (int r = ty; r < 32; r += 8)
    tile[r][tx] = bf16bits(In[(size_t)(bk + r)*C + bn + tx]);
  __syncthreads();
  for (int r = ty; r < 32; r += 8)
    Out[(size_t)(bn + r)*R + bk + tx] = tile[tx][r];
}

// ---------------- ktr_split: transposed hi/lo split of In (f32) ----------------
__global__ __launch_bounds__(256) void ktr_split(const float* __restrict__ In,
                                                 unsigned short* __restrict__ OutHi,
                                                 unsigned short* __restrict__ OutLo,
                                                 int R, int C) {
  __shared__ unsigned short thi[32][33];
  __shared__ unsigned short tlo[32][33];
  int bk = blockIdx.x*32, bn = blockIdx.y*32;
  int tx = threadIdx.x & 31, ty = threadIdx.x >> 5;
  for (int r = ty; r < 32; r += 8) {
    float f = In[(size_t)(bk + r)*C + bn + tx];
    __hip_bfloat16 h = __float2bfloat16(f);
    float fh = __bfloat162float(h);
    thi[r][tx] = *reinterpret_cast<unsigned short*>(&h);
    tlo[r][tx] = bf16bits(f - fh);
  }
  __syncthreads();
  for (int r = ty; r < 32; r += 8) {
    OutHi[(size_t)(bn + r)*R + bk + tx] = thi[tx][r];
    OutLo[(size_t)(bn + r)*R + bk + tx] = tlo[tx][r];
  }
}

// ---------------- K1: ns0 (+)= A @ BT (bf16 MFMA, round-3-validated 2-phase 128^2) ----------------
#define K1BK 32
#define K1NK 32   // K=1024
template<int ACC>
__global__ __launch_bounds__(256) void k1_mfma(const unsigned short* __restrict__ A,   // [256][1024]
                                               const unsigned short* __restrict__ BT,  // [2048][1024]
                                               float* __restrict__ NS0) {              // [256][2048]
  __shared__ short As[2][128*K1BK];
  __shared__ short Bs[2][128*K1BK];
  int tid = threadIdx.x;
  int l = tid & 63, w = tid >> 6;
  int wr = (w >> 1) << 6, wc = (w & 1) << 6;
  int lr = l & 15, lg = l >> 4;
  size_t gm = (size_t)blockIdx.x * 128;
  size_t gn = (size_t)blockIdx.y * 128;
  int c0 = w*2, c1 = w*2 + 1;
  int srow = l >> 2;
  int scol = ((l & 3)*8) ^ (((l >> 2) & 6) << 2);
  const unsigned short* a0 = &A [(gm + c0*16 + srow)*1024 + scol];
  const unsigned short* a1 = &A [(gm + c1*16 + srow)*1024 + scol];
  const unsigned short* b0 = &BT[(gn + c0*16 + srow)*1024 + scol];
  const unsigned short* b1 = &BT[(gn + c1*16 + srow)*1024 + scol];
  int rdswz = (lr & 6) << 2;
  f32x4 acc[4][4] = {};
  GLD16(a0, &As[0][c0*512]); GLD16(a1, &As[0][c1*512]);
  GLD16(b0, &Bs[0][c0*512]); GLD16(b1, &Bs[0][c1*512]);
  __syncthreads();
  #pragma unroll 2
  for (int t = 0; t < K1NK; ++t) {
    int cur = t & 1;
    if (t + 1 < K1NK) {
      int nxt = cur ^ 1; size_t ko = (size_t)(t + 1)*K1BK;
      GLD16(a0 + ko, &As[nxt][c0*512]); GLD16(a1 + ko, &As[nxt][c1*512]);
      GLD16(b0 + ko, &Bs[nxt][c0*512]); GLD16(b1 + ko, &Bs[nxt][c1*512]);
    }
    short8 af[4], bfr[4];
    #pragma unroll
    for (int mi = 0; mi < 4; ++mi)
      af[mi] = *reinterpret_cast<const short8*>(&As[cur][(wr + mi*16 + lr)*K1BK + (lg*8 ^ rdswz)]);
    #pragma unroll
    for (int ni = 0; ni < 4; ++ni)
      bfr[ni] = *reinterpret_cast<const short8*>(&Bs[cur][(wc + ni*16 + lr)*K1BK + (lg*8 ^ rdswz)]);
    #pragma unroll
    for (int mi = 0; mi < 4; ++mi)
      #pragma unroll
      for (int ni = 0; ni < 4; ++ni)
        acc[mi][ni] = __builtin_amdgcn_mfma_f32_16x16x32_bf16(af[mi], bfr[ni], acc[mi][ni], 0, 0, 0);
    __syncthreads();
  }
  #pragma unroll
  for (int mi = 0; mi < 4; ++mi)
    #pragma unroll
    for (int ni = 0; ni < 4; ++ni)
      #pragma unroll
      for (int q = 0; q < 4; ++q) {
        size_t o = (gm + wr + mi*16 + lg*4 + q)*Hdim + gn + wc + ni*16 + lr;
        if (ACC) NS0[o] = __fadd_rn(NS0[o], acc[mi][ni][q]);
        else     NS0[o] = acc[mi][ni][q];
      }
}

// ---------------- K2: layer-0 sim; writes mem0_rec, spk_rec, t=0 zeros, bf16 Z ----------------
__global__ __launch_bounds__(256) void k2_sim(const float* __restrict__ NS0,
                                              float* __restrict__ out,
                                              unsigned short* __restrict__ Zb) {
  size_t idx = (size_t)blockIdx.x*256 + threadIdx.x;  // b*H + j
  float ns = NS0[idx];
  float* mem = out + OUT_MEM;
  float* spk = out + OUT_SPK;
  mem[idx] = 0.f;
  mem[BH + idx] = 0.f;
  spk[idx] = 0.f;
  float m = 0.f;
  for (int t = 1; t < Tdim; ++t) {
    m = __fadd_rn(__fmul_rn(0.9f, m), ns);
    bool sp = m > 1.0f;
    float z = sp ? 1.f : 0.f;
    if (sp) m = 0.f;
    mem[(size_t)(2*t)*BH + idx] = m;
    spk[(size_t)t*BH + idx] = z;
    Zb[(size_t)(t-1)*BH + idx] = sp ? (unsigned short)0x3F80 : (unsigned short)0;
  }
}

// ---------------- K3: C = Z @ W1, 256^2 tile, BK=64, 8-wave, 4-phase/K-tile counted-vmcnt pipeline ----
#define NKT3 32   // 2048/64

#define K3_ST(g, ldsarr, half, kt) do { \
  int _b = (kt) & 1; \
  const unsigned short* _p = (g) + (size_t)(kt)*64 + (size_t)(half)*128*Hdim; \
  GLD16(_p,          &ldsarr[_b][(half)*8192 + w*1024]); \
  GLD16(_p + 8*Hdim, &ldsarr[_b][(half)*8192 + w*1024 + 512]); \
} while(0)

#define K3_LDA(h) do { \
  _Pragma("unroll") \
  for (int mi = 0; mi < 4; ++mi) \
    _Pragma("unroll") \
    for (int ks = 0; ks < 2; ++ks) \
      af[mi][ks] = *reinterpret_cast<const short8*>(&As[bb][((h)*128 + wm*64 + mi*16 + lr)*64 + ((ks*32 + lg*8) ^ rs)]); \
} while(0)

#define K3_LDB(v, bf) do { \
  _Pragma("unroll") \
  for (int ni = 0; ni < 2; ++ni) \
    _Pragma("unroll") \
    for (int ks = 0; ks < 2; ++ks) \
      bf[ni][ks] = *reinterpret_cast<const short8*>(&Bs[bb][((v)*128 + wn*32 + ni*16 + lr)*64 + ((ks*32 + lg*8) ^ rs)]); \
} while(0)

#define K3_MFMA(h, v, bf) do { \
  __builtin_amdgcn_s_setprio(1); \
  _Pragma("unroll") \
  for (int ks = 0; ks < 2; ++ks) \
    _Pragma("unroll") \
    for (int mi = 0; mi < 4; ++mi) \
      _Pragma("unroll") \
      for (int ni = 0; ni < 2; ++ni) \
        acc[(h)*4+mi][(v)*2+ni] = __builtin_amdgcn_mfma_f32_16x16x32_bf16(af[mi][ks], bf[ni][ks], acc[(h)*4+mi][(v)*2+ni], 0, 0, 0); \
  __builtin_amdgcn_s_setprio(0); \
} while(0)

// CB=0: fp32 C written in-place into mem_rec[t][1] planes (round-6 validated path)
// CB=1: bf16 C written contiguously to cbuf (k4_cbuf expands planes)
template<int CB>
__global__ __launch_bounds__(512, 2) void k3_gemm(const unsigned short* __restrict__ A,   // Zb [M3][2048]
                                                  const unsigned short* __restrict__ BT,  // W1T [2048][2048]
                                                  float* __restrict__ mem1,               // out + OUT_MEM
                                                  unsigned short* __restrict__ cbuf) {    // [99][256][2048] bf16
  __shared__ short As[2][256*64];   // 64 KB
  __shared__ short Bs[2][256*64];   // 64 KB
  int tid = threadIdx.x;
  int l = tid & 63;
  int w = tid >> 6;                 // wave 0..7
  int wm = w >> 2, wn = w & 3;      // 2M x 4N
  int lr = l & 15, lg = l >> 4;
  int rs = (lr & 7) << 3;           // read-side XOR, shorts (16B-slot granularity)

  // T1: grid 792 = 8*99 bijective, ntile fast
  int lin = blockIdx.x;
  int wg = (lin & 7)*99 + (lin >> 3);
  int mtile = wg >> 3, ntile = wg & 7;
  size_t gm = (size_t)mtile * 256;
  size_t gn = (size_t)ntile * 256;

  // staging: rule-21 pre-swizzled global source, linear LDS dest (row=l>>3, slot=l&7)
  int srow8 = l >> 3, sslot = l & 7;
  int scol3 = (sslot ^ srow8) << 3;
  const unsigned short* gA = &A [(gm + w*16 + srow8)*Hdim + scol3];
  const unsigned short* gB = &BT[(gn + w*16 + srow8)*Hdim + scol3];

  f32x4 acc[8][4] = {};

  // prologue: tile0 (4 half-tiles) + A-lo(1), B-hi(1)  -> 12 outstanding loads
  K3_ST(gA, As, 0, 0); K3_ST(gB, Bs, 0, 0);
  K3_ST(gA, As, 1, 0); K3_ST(gB, Bs, 1, 0);
  K3_ST(gA, As, 0, 1); K3_ST(gB, Bs, 1, 1);

  for (int kt = 0; kt < NKT3; ++kt) {
    int bb = kt & 1;
    // entry: tile kt's 4 half-tiles are the 8 oldest outstanding -> counted wait (T4)
    if (kt == NKT3 - 1) asm volatile("s_waitcnt vmcnt(0)" ::: "memory");
    else                asm volatile("s_waitcnt vmcnt(4)" ::: "memory");
    __builtin_amdgcn_s_barrier();
    asm volatile("" ::: "memory");

    short8 af[4][2], bfl[2][2], bfh[2][2];

    // P1 (h0,v0): A-lo last LDS-read here; stage A-hi(kt+1) (region idle since kt-1.p3)
    K3_LDA(0); K3_LDB(0, bfl);
    if (kt + 1 < NKT3) K3_ST(gA, As, 1, kt + 1);
    BARL(); LGKM0();
    K3_MFMA(0, 0, bfl);
    BARL();
    // P2 (h0,v1): B-hi read; stage B-lo(kt+1) (idle since kt-1.p1)
    K3_LDB(1, bfh);
    if (kt + 1 < NKT3) K3_ST(gB, Bs, 0, kt + 1);
    BARL(); LGKM0();
    K3_MFMA(0, 1, bfh);
    BARL();
    // P3 (h1,v1): A-hi read; stage A-lo(kt+2) (A-lo reads finished >=2 barriers ago)
    K3_LDA(1);
    if (kt + 2 < NKT3) K3_ST(gA, As, 0, kt + 2);
    BARL(); LGKM0();
    K3_MFMA(1, 1, bfh);
    BARL();
    // P4 (h1,v0): no reads (bfl reused); stage B-hi(kt+2) (B-hi reads finished >=2 barriers ago)
    if (kt + 2 < NKT3) K3_ST(gB, Bs, 1, kt + 2);
    K3_MFMA(1, 0, bfl);
    // group-end barrier == next iteration's entry barrier
  }

  // epilogue: M-tile == C plane t = mtile+1
  if (CB) {
    unsigned short* cp = cbuf + (size_t)mtile*BH + gn;
    #pragma unroll
    for (int hh = 0; hh < 2; ++hh)
      #pragma unroll
      for (int mi = 0; mi < 4; ++mi)
        #pragma unroll
        for (int vv = 0; vv < 2; ++vv)
          #pragma unroll
          for (int ni = 0; ni < 2; ++ni)
            #pragma unroll
            for (int q = 0; q < 4; ++q) {
              int b   = hh*128 + wm*64 + mi*16 + lg*4 + q;
              int col = vv*128 + wn*32 + ni*16 + lr;
              cp[(size_t)b*Hdim + col] = bf16bits(acc[hh*4+mi][vv*2+ni][q]);
            }
  } else {
    float* plane = mem1 + (size_t)(2*mtile + 3)*BH + gn;
    #pragma unroll
    for (int hh = 0; hh < 2; ++hh)
      #pragma unroll
      for (int mi = 0; mi < 4; ++mi)
        #pragma unroll
        for (int vv = 0; vv < 2; ++vv)
          #pragma unroll
          for (int ni = 0; ni < 2; ++ni)
            #pragma unroll
            for (int q = 0; q < 4; ++q) {
              int b   = hh*128 + wm*64 + mi*16 + lg*4 + q;
              int col = vv*128 + wn*32 + ni*16 + lr;
              plane[(size_t)b*Hdim + col] = acc[hh*4+mi][vv*2+ni][q];
            }
  }
}

// ---------------- K4a: in-place temporal recurrence over fp32 C planes ----------------
__global__ __launch_bounds__(256) void k4_rec(float* __restrict__ out) {
  size_t idx = (size_t)blockIdx.x*256 + threadIdx.x;
  float* mem = out + OUT_MEM;
  float s = 0.f, m = 0.f;
  for (int t = 1; t < Tdim; ++t) {
    float* p = &mem[(size_t)(2*t + 1)*BH + idx];
    float c = *p;
    s = __fadd_rn(__fmul_rn(0.95f, s), c);
    m = __fadd_rn(__fmul_rn(0.9f, m), s);
    *p = m;
  }
  out[idx] = m;
}

// ---------------- K4b: recurrence reading bf16 cbuf, writing fp32 planes ----------------
__global__ __launch_bounds__(256) void k4_rec_cb(const unsigned short* __restrict__ C,
                                                 float* __restrict__ out) {
  size_t idx = (size_t)blockIdx.x*256 + threadIdx.x;
  float* mem = out + OUT_MEM;
  float s = 0.f, m = 0.f;
  for (int t = 1; t < Tdim; ++t) {
    unsigned int u = C[(size_t)(t-1)*BH + idx];
    float c = __uint_as_float(u << 16);   // bf16 -> f32 exact
    s = __fadd_rn(__fmul_rn(0.95f, s), c);
    m = __fadd_rn(__fmul_rn(0.9f, m), s);
    mem[(size_t)(2*t + 1)*BH + idx] = m;
  }
  out[idx] = m;
}

extern "C" void kernel_launch(void* const* d_in, const int* in_sizes, int n_in,
                              void* d_out, int out_size, void* d_ws, size_t ws_size,
                              hipStream_t stream) {
  const float* X  = (const float*)d_in[0];
  const float* W0 = (const float*)d_in[1];
  const float* W1 = (const float*)d_in[2];
  float* out = (float*)d_out;
  char* ws = (char*)d_ws;

  float*          ns0  = (float*)ws;                                   // 2 MiB @0
  unsigned short* w1t  = (unsigned short*)(ws + (2ull  << 20));        // 8 MiB @2M
  unsigned short* zb   = (unsigned short*)(ws + (10ull << 20));        // 99 MiB @10M (fits; verified)
  unsigned short* cbuf = (unsigned short*)(ws + (10ull << 20) + ZBYTES); // 99 MiB, optional
  size_t needCb = (10ull << 20) + 2*ZBYTES;
  int useCb = (ws_size >= needCb) ? 1 : 0;
  // hi/lo split inputs live INSIDE the zb region; consumed by k1 before k2 overwrites with Zb
  unsigned short* xhi = (unsigned short*)(ws + (10ull << 20));              // 0.5 MiB
  unsigned short* xlo = (unsigned short*)(ws + (10ull << 20) + (512<<10));  // 0.5 MiB
  unsigned short* whi = (unsigned short*)(ws + (11ull << 20));              // 4 MiB
  unsigned short* wlo = (unsigned short*)(ws + (15ull << 20));              // 4 MiB

  kcvt_split<<<dim3(256),     256, 0, stream>>>(X, xhi, xlo);
  ktr_split <<<dim3(32, 64),  256, 0, stream>>>(W0, whi, wlo, 1024, 2048);  // W0T hi/lo [2048][1024]
  ktr_bf16  <<<dim3(64, 64),  256, 0, stream>>>(W1, w1t, 2048, 2048);       // W1T [2048][2048]
  // ns0 = xhi@whi + xhi@wlo + xlo@whi  (fp32 accumulate, fixed order -> deterministic)
  k1_mfma<0><<<dim3(2, 16),   256, 0, stream>>>(xhi, whi, ns0);
  k1_mfma<1><<<dim3(2, 16),   256, 0, stream>>>(xhi, wlo, ns0);
  k1_mfma<1><<<dim3(2, 16),   256, 0, stream>>>(xlo, whi, ns0);
  k2_sim <<<dim3(BH/256),     256, 0, stream>>>(ns0, out, zb);
  if (useCb) {
    k3_gemm<1><<<dim3((M3/256)*(Hdim/256)), 512, 0, stream>>>(zb, w1t, out + OUT_MEM, cbuf);
    k4_rec_cb<<<dim3(BH/256), 256, 0, stream>>>(cbuf, out);
  } else {
    k3_gemm<0><<<dim3((M3/256)*(Hdim/256)), 512, 0, stream>>>(zb, w1t, out + OUT_MEM, cbuf);
    k4_rec  <<<dim3(BH/256),  256, 0, stream>>>(out);
  }
}

// Round 8
// 434.399 us; speedup vs baseline: 1.5870x; 1.1246x over previous
//
#include <hip/hip_runtime.h>
#include <hip/hip_bf16.h>

#define Bdim 256
#define Ddim 1024
#define Hdim 2048
#define Tdim 100
#define BH (Bdim*Hdim)            // 524288
#define M3 ((Tdim-1)*Bdim)        // 25344
#define ZBYTES ((size_t)M3*Hdim*2)   // 103,809,024 B

#define OUT_MEM ((size_t)BH)                          // mem_rec starts after out0
#define OUT_SPK ((size_t)BH + (size_t)Tdim*2*BH)      // spk_rec after mem_rec

typedef __attribute__((ext_vector_type(8))) short short8;
typedef __attribute__((ext_vector_type(4))) float f32x4;

// async global->LDS, 16B per lane, LDS dest = wave-uniform base + lane*16
#define GLD16(g, l) __builtin_amdgcn_global_load_lds( \
    (__attribute__((address_space(1))) void*)(g), \
    (__attribute__((address_space(3))) void*)(l), 16, 0, 0)

// Lightweight barrier: memory clobbers pin LDS/VMEM ops to their phase (race
// safety) without sched_barrier(0) order-pinning (m141 lesson). ds_read->MFMA
// ordering is left to the compiler's fine-grained lgkmcnt (m97 finding).
#define BARL() do { asm volatile("" ::: "memory"); __builtin_amdgcn_s_barrier(); \
                    asm volatile("" ::: "memory"); } while(0)

static __device__ __forceinline__ unsigned short bf16bits(float f) {
  __hip_bfloat16 h = __float2bfloat16(f);
  return *reinterpret_cast<unsigned short*>(&h);
}

// ---------------- kcvt_split: X f32 -> bf16 hi + bf16 lo(residual) ----------------
__global__ __launch_bounds__(256) void kcvt_split(const float* __restrict__ X,
                                                  unsigned short* __restrict__ Xhi,
                                                  unsigned short* __restrict__ Xlo) {
  int i = (blockIdx.x*256 + threadIdx.x)*4;
  float4 v = *reinterpret_cast<const float4*>(&X[i]);
  ushort4 ph, pl;
  float f, fh;
  f = v.x; { __hip_bfloat16 h = __float2bfloat16(f); fh = __bfloat162float(h); ph.x = *reinterpret_cast<unsigned short*>(&h); } pl.x = bf16bits(f - fh);
  f = v.y; { __hip_bfloat16 h = __float2bfloat16(f); fh = __bfloat162float(h); ph.y = *reinterpret_cast<unsigned short*>(&h); } pl.y = bf16bits(f - fh);
  f = v.z; { __hip_bfloat16 h = __float2bfloat16(f); fh = __bfloat162float(h); ph.z = *reinterpret_cast<unsigned short*>(&h); } pl.z = bf16bits(f - fh);
  f = v.w; { __hip_bfloat16 h = __float2bfloat16(f); fh = __bfloat162float(h); ph.w = *reinterpret_cast<unsigned short*>(&h); } pl.w = bf16bits(f - fh);
  *reinterpret_cast<ushort4*>(&Xhi[i]) = ph;
  *reinterpret_cast<ushort4*>(&Xlo[i]) = pl;
}

// ---------------- ktr_bf16: Out[C][R] = bf16(In[R][C]^T) ----------------
__global__ __launch_bounds__(256) void ktr_bf16(const float* __restrict__ In,
                                                unsigned short* __restrict__ Out,
                                                int R, int C) {
  __shared__ unsigned short tile[32][33];
  int bk = blockIdx.x*32, bn = blockIdx.y*32;
  int tx = threadIdx.x & 31, ty = threadIdx.x >> 5;
  for (int r = ty; r < 32; r += 8)
    tile[r][tx] = bf16bits(In[(size_t)(bk + r)*C + bn + tx]);
  __syncthreads();
  for (int r = ty; r < 32; r += 8)
    Out[(size_t)(bn + r)*R + bk + tx] = tile[tx][r];
}

// ---------------- ktr_split: transposed hi/lo split of In (f32) ----------------
__global__ __launch_bounds__(256) void ktr_split(const float* __restrict__ In,
                                                 unsigned short* __restrict__ OutHi,
                                                 unsigned short* __restrict__ OutLo,
                                                 int R, int C) {
  __shared__ unsigned short thi[32][33];
  __shared__ unsigned short tlo[32][33];
  int bk = blockIdx.x*32, bn = blockIdx.y*32;
  int tx = threadIdx.x & 31, ty = threadIdx.x >> 5;
  for (int r = ty; r < 32; r += 8) {
    float f = In[(size_t)(bk + r)*C + bn + tx];
    __hip_bfloat16 h = __float2bfloat16(f);
    float fh = __bfloat162float(h);
    thi[r][tx] = *reinterpret_cast<unsigned short*>(&h);
    tlo[r][tx] = bf16bits(f - fh);
  }
  __syncthreads();
  for (int r = ty; r < 32; r += 8) {
    OutHi[(size_t)(bn + r)*R + bk + tx] = thi[tx][r];
    OutLo[(size_t)(bn + r)*R + bk + tx] = tlo[tx][r];
  }
}

// ---------------- K1 fused: ns0 = xhi@whiT + xhi@wloT + xlo@whiT (one kernel) ----------------
// 64x64 tiles, grid 4x32 = 128 blocks (vs 3 sequential 32-block launches).
// Staging/swizzle/fragment pattern identical to the validated k1 (quarter size).
#define K1F_NK 32   // K = 1024, BK = 32
__global__ __launch_bounds__(256) void k1_fused(const unsigned short* __restrict__ xhi,
                                                const unsigned short* __restrict__ xlo,
                                                const unsigned short* __restrict__ whiT,
                                                const unsigned short* __restrict__ wloT,
                                                float* __restrict__ NS0) {
  __shared__ short Ah[2][64*32], Al[2][64*32];   // 4 KB each buf
  __shared__ short Bh[2][64*32], Bl[2][64*32];   // total 32 KB
  int tid = threadIdx.x;
  int l = tid & 63, w = tid >> 6;      // 4 waves
  int wm = w >> 1, wn = w & 1;         // 2x2 waves, each 32x32 out
  int lr = l & 15, lg = l >> 4;
  size_t gm = (size_t)blockIdx.x * 64;
  size_t gn = (size_t)blockIdx.y * 64;
  int srow = l >> 2;
  int scol = ((l & 3)*8) ^ (((l >> 2) & 6) << 2);   // validated involution
  const unsigned short* gah = &xhi [(gm + w*16 + srow)*1024 + scol];
  const unsigned short* gal = &xlo [(gm + w*16 + srow)*1024 + scol];
  const unsigned short* gbh = &whiT[(gn + w*16 + srow)*1024 + scol];
  const unsigned short* gbl = &wloT[(gn + w*16 + srow)*1024 + scol];
  int rdswz = (lr & 6) << 2;
  f32x4 acc[2][2] = {};
  GLD16(gah, &Ah[0][w*512]); GLD16(gal, &Al[0][w*512]);
  GLD16(gbh, &Bh[0][w*512]); GLD16(gbl, &Bl[0][w*512]);
  __syncthreads();
  #pragma unroll 2
  for (int t = 0; t < K1F_NK; ++t) {
    int cur = t & 1;
    if (t + 1 < K1F_NK) {
      int nxt = cur ^ 1; size_t ko = (size_t)(t + 1)*32;
      GLD16(gah + ko, &Ah[nxt][w*512]); GLD16(gal + ko, &Al[nxt][w*512]);
      GLD16(gbh + ko, &Bh[nxt][w*512]); GLD16(gbl + ko, &Bl[nxt][w*512]);
    }
    short8 ah[2], al[2], bh[2], bl[2];
    #pragma unroll
    for (int mi = 0; mi < 2; ++mi) {
      int ro = (wm*32 + mi*16 + lr)*32 + (lg*8 ^ rdswz);
      ah[mi] = *reinterpret_cast<const short8*>(&Ah[cur][ro]);
      al[mi] = *reinterpret_cast<const short8*>(&Al[cur][ro]);
    }
    #pragma unroll
    for (int ni = 0; ni < 2; ++ni) {
      int ro = (wn*32 + ni*16 + lr)*32 + (lg*8 ^ rdswz);
      bh[ni] = *reinterpret_cast<const short8*>(&Bh[cur][ro]);
      bl[ni] = *reinterpret_cast<const short8*>(&Bl[cur][ro]);
    }
    #pragma unroll
    for (int mi = 0; mi < 2; ++mi)
      #pragma unroll
      for (int ni = 0; ni < 2; ++ni) {
        acc[mi][ni] = __builtin_amdgcn_mfma_f32_16x16x32_bf16(ah[mi], bh[ni], acc[mi][ni], 0, 0, 0);
        acc[mi][ni] = __builtin_amdgcn_mfma_f32_16x16x32_bf16(ah[mi], bl[ni], acc[mi][ni], 0, 0, 0);
        acc[mi][ni] = __builtin_amdgcn_mfma_f32_16x16x32_bf16(al[mi], bh[ni], acc[mi][ni], 0, 0, 0);
      }
    __syncthreads();
  }
  #pragma unroll
  for (int mi = 0; mi < 2; ++mi)
    #pragma unroll
    for (int ni = 0; ni < 2; ++ni)
      #pragma unroll
      for (int q = 0; q < 4; ++q)
        NS0[(gm + wm*32 + mi*16 + lg*4 + q)*Hdim + gn + wn*32 + ni*16 + lr] = acc[mi][ni][q];
}

// ---------------- K2: layer-0 sim; writes mem0_rec, spk_rec, t=0 zeros, bf16 Z ----------------
__global__ __launch_bounds__(256) void k2_sim(const float* __restrict__ NS0,
                                              float* __restrict__ out,
                                              unsigned short* __restrict__ Zb) {
  size_t idx = (size_t)blockIdx.x*256 + threadIdx.x;  // b*H + j
  float ns = NS0[idx];
  float* mem = out + OUT_MEM;
  float* spk = out + OUT_SPK;
  mem[idx] = 0.f;
  mem[BH + idx] = 0.f;
  spk[idx] = 0.f;
  float m = 0.f;
  for (int t = 1; t < Tdim; ++t) {
    m = __fadd_rn(__fmul_rn(0.9f, m), ns);
    bool sp = m > 1.0f;
    float z = sp ? 1.f : 0.f;
    if (sp) m = 0.f;
    mem[(size_t)(2*t)*BH + idx] = m;
    spk[(size_t)t*BH + idx] = z;
    Zb[(size_t)(t-1)*BH + idx] = sp ? (unsigned short)0x3F80 : (unsigned short)0;
  }
}

// ---------------- K3: C = Z @ W1, 256^2 tile, BK=64, 8-wave, 4-phase/K-tile counted-vmcnt pipeline ----
#define NKT3 32   // 2048/64

#define K3_ST(g, ldsarr, half, kt) do { \
  int _b = (kt) & 1; \
  const unsigned short* _p = (g) + (size_t)(kt)*64 + (size_t)(half)*128*Hdim; \
  GLD16(_p,          &ldsarr[_b][(half)*8192 + w*1024]); \
  GLD16(_p + 8*Hdim, &ldsarr[_b][(half)*8192 + w*1024 + 512]); \
} while(0)

#define K3_LDA(h) do { \
  _Pragma("unroll") \
  for (int mi = 0; mi < 4; ++mi) \
    _Pragma("unroll") \
    for (int ks = 0; ks < 2; ++ks) \
      af[mi][ks] = *reinterpret_cast<const short8*>(&As[bb][((h)*128 + wm*64 + mi*16 + lr)*64 + ((ks*32 + lg*8) ^ rs)]); \
} while(0)

#define K3_LDB(v, bf) do { \
  _Pragma("unroll") \
  for (int ni = 0; ni < 2; ++ni) \
    _Pragma("unroll") \
    for (int ks = 0; ks < 2; ++ks) \
      bf[ni][ks] = *reinterpret_cast<const short8*>(&Bs[bb][((v)*128 + wn*32 + ni*16 + lr)*64 + ((ks*32 + lg*8) ^ rs)]); \
} while(0)

#define K3_MFMA(h, v, bf) do { \
  __builtin_amdgcn_s_setprio(1); \
  _Pragma("unroll") \
  for (int ks = 0; ks < 2; ++ks) \
    _Pragma("unroll") \
    for (int mi = 0; mi < 4; ++mi) \
      _Pragma("unroll") \
      for (int ni = 0; ni < 2; ++ni) \
        acc[(h)*4+mi][(v)*2+ni] = __builtin_amdgcn_mfma_f32_16x16x32_bf16(af[mi][ks], bf[ni][ks], acc[(h)*4+mi][(v)*2+ni], 0, 0, 0); \
  __builtin_amdgcn_s_setprio(0); \
} while(0)

// CB=0: fp32 C written in-place into mem_rec[t][1] planes
// CB=1: bf16 C written contiguously to cbuf (k4_rec_cb expands planes)
template<int CB>
__global__ __launch_bounds__(512, 2) void k3_gemm(const unsigned short* __restrict__ A,   // Zb [M3][2048]
                                                  const unsigned short* __restrict__ BT,  // W1T [2048][2048]
                                                  float* __restrict__ mem1,               // out + OUT_MEM
                                                  unsigned short* __restrict__ cbuf) {    // [99][256][2048] bf16
  __shared__ short As[2][256*64];   // 64 KB
  __shared__ short Bs[2][256*64];   // 64 KB
  int tid = threadIdx.x;
  int l = tid & 63;
  int w = tid >> 6;                 // wave 0..7
  int wm = w >> 2, wn = w & 3;      // 2M x 4N
  int lr = l & 15, lg = l >> 4;
  int rs = (lr & 7) << 3;           // read-side XOR, shorts (16B-slot granularity)

  // T1: grid 792 = 8*99 bijective, ntile fast
  int lin = blockIdx.x;
  int wg = (lin & 7)*99 + (lin >> 3);
  int mtile = wg >> 3, ntile = wg & 7;
  size_t gm = (size_t)mtile * 256;
  size_t gn = (size_t)ntile * 256;

  // staging: rule-21 pre-swizzled global source, linear LDS dest (row=l>>3, slot=l&7)
  int srow8 = l >> 3, sslot = l & 7;
  int scol3 = (sslot ^ srow8) << 3;
  const unsigned short* gA = &A [(gm + w*16 + srow8)*Hdim + scol3];
  const unsigned short* gB = &BT[(gn + w*16 + srow8)*Hdim + scol3];

  f32x4 acc[8][4] = {};

  // prologue: tile0 (4 half-tiles) + A-lo(1), B-hi(1)  -> 12 outstanding loads
  K3_ST(gA, As, 0, 0); K3_ST(gB, Bs, 0, 0);
  K3_ST(gA, As, 1, 0); K3_ST(gB, Bs, 1, 0);
  K3_ST(gA, As, 0, 1); K3_ST(gB, Bs, 1, 1);

  for (int kt = 0; kt < NKT3; ++kt) {
    int bb = kt & 1;
    // entry: tile kt's 4 half-tiles are the 8 oldest outstanding -> counted wait (T4)
    if (kt == NKT3 - 1) asm volatile("s_waitcnt vmcnt(0)" ::: "memory");
    else                asm volatile("s_waitcnt vmcnt(4)" ::: "memory");
    __builtin_amdgcn_s_barrier();
    asm volatile("" ::: "memory");

    short8 af[4][2], bfl[2][2], bfh[2][2];

    // P1 (h0,v0): A-lo last LDS-read here; stage A-hi(kt+1) (region idle since kt-1.p3)
    K3_LDA(0); K3_LDB(0, bfl);
    if (kt + 1 < NKT3) K3_ST(gA, As, 1, kt + 1);
    BARL();
    K3_MFMA(0, 0, bfl);
    BARL();
    // P2 (h0,v1): B-hi read; stage B-lo(kt+1) (idle since kt-1.p1)
    K3_LDB(1, bfh);
    if (kt + 1 < NKT3) K3_ST(gB, Bs, 0, kt + 1);
    BARL();
    K3_MFMA(0, 1, bfh);
    BARL();
    // P3 (h1,v1): A-hi read; stage A-lo(kt+2) (A-lo reads finished >=2 barriers ago)
    K3_LDA(1);
    if (kt + 2 < NKT3) K3_ST(gA, As, 0, kt + 2);
    BARL();
    K3_MFMA(1, 1, bfh);
    BARL();
    // P4 (h1,v0): no reads (bfl reused); stage B-hi(kt+2) (B-hi reads finished >=2 barriers ago)
    if (kt + 2 < NKT3) K3_ST(gB, Bs, 1, kt + 2);
    K3_MFMA(1, 0, bfl);
    // group-end barrier == next iteration's entry barrier
  }

  // epilogue: M-tile == C plane t = mtile+1
  if (CB) {
    unsigned short* cp = cbuf + (size_t)mtile*BH + gn;
    #pragma unroll
    for (int hh = 0; hh < 2; ++hh)
      #pragma unroll
      for (int mi = 0; mi < 4; ++mi)
        #pragma unroll
        for (int vv = 0; vv < 2; ++vv)
          #pragma unroll
          for (int ni = 0; ni < 2; ++ni)
            #pragma unroll
            for (int q = 0; q < 4; ++q) {
              int b   = hh*128 + wm*64 + mi*16 + lg*4 + q;
              int col = vv*128 + wn*32 + ni*16 + lr;
              cp[(size_t)b*Hdim + col] = bf16bits(acc[hh*4+mi][vv*2+ni][q]);
            }
  } else {
    float* plane = mem1 + (size_t)(2*mtile + 3)*BH + gn;
    #pragma unroll
    for (int hh = 0; hh < 2; ++hh)
      #pragma unroll
      for (int mi = 0; mi < 4; ++mi)
        #pragma unroll
        for (int vv = 0; vv < 2; ++vv)
          #pragma unroll
          for (int ni = 0; ni < 2; ++ni)
            #pragma unroll
            for (int q = 0; q < 4; ++q) {
              int b   = hh*128 + wm*64 + mi*16 + lg*4 + q;
              int col = vv*128 + wn*32 + ni*16 + lr;
              plane[(size_t)b*Hdim + col] = acc[hh*4+mi][vv*2+ni][q];
            }
  }
}

// ---------------- K4a: in-place temporal recurrence over fp32 C planes ----------------
__global__ __launch_bounds__(256) void k4_rec(float* __restrict__ out) {
  size_t idx = (size_t)blockIdx.x*256 + threadIdx.x;
  float* mem = out + OUT_MEM;
  float s = 0.f, m = 0.f;
  for (int t = 1; t < Tdim; ++t) {
    float* p = &mem[(size_t)(2*t + 1)*BH + idx];
    float c = *p;
    s = __fadd_rn(__fmul_rn(0.95f, s), c);
    m = __fadd_rn(__fmul_rn(0.9f, m), s);
    *p = m;
  }
  out[idx] = m;
}

// ---------------- K4b: recurrence reading bf16 cbuf, writing fp32 planes ----------------
__global__ __launch_bounds__(256) void k4_rec_cb(const unsigned short* __restrict__ C,
                                                 float* __restrict__ out) {
  size_t idx = (size_t)blockIdx.x*256 + threadIdx.x;
  float* mem = out + OUT_MEM;
  float s = 0.f, m = 0.f;
  for (int t = 1; t < Tdim; ++t) {
    unsigned int u = C[(size_t)(t-1)*BH + idx];
    float c = __uint_as_float(u << 16);   // bf16 -> f32 exact
    s = __fadd_rn(__fmul_rn(0.95f, s), c);
    m = __fadd_rn(__fmul_rn(0.9f, m), s);
    mem[(size_t)(2*t + 1)*BH + idx] = m;
  }
  out[idx] = m;
}

extern "C" void kernel_launch(void* const* d_in, const int* in_sizes, int n_in,
                              void* d_out, int out_size, void* d_ws, size_t ws_size,
                              hipStream_t stream) {
  const float* X  = (const float*)d_in[0];
  const float* W0 = (const float*)d_in[1];
  const float* W1 = (const float*)d_in[2];
  float* out = (float*)d_out;
  char* ws = (char*)d_ws;

  float*          ns0  = (float*)ws;                                   // 2 MiB @0
  unsigned short* w1t  = (unsigned short*)(ws + (2ull  << 20));        // 8 MiB @2M
  unsigned short* zb   = (unsigned short*)(ws + (10ull << 20));        // 99 MiB @10M (fits; verified)
  unsigned short* cbuf = (unsigned short*)(ws + (10ull << 20) + ZBYTES); // 99 MiB, optional
  size_t needCb = (10ull << 20) + 2*ZBYTES;
  int useCb = (ws_size >= needCb) ? 1 : 0;
  // hi/lo split inputs live INSIDE the zb region; consumed by k1 before k2 overwrites with Zb
  unsigned short* xhi = (unsigned short*)(ws + (10ull << 20));              // 0.5 MiB
  unsigned short* xlo = (unsigned short*)(ws + (10ull << 20) + (512<<10));  // 0.5 MiB
  unsigned short* whi = (unsigned short*)(ws + (11ull << 20));              // 4 MiB
  unsigned short* wlo = (unsigned short*)(ws + (15ull << 20));              // 4 MiB

  kcvt_split<<<dim3(256),     256, 0, stream>>>(X, xhi, xlo);
  ktr_split <<<dim3(32, 64),  256, 0, stream>>>(W0, whi, wlo, 1024, 2048);  // W0T hi/lo [2048][1024]
  ktr_bf16  <<<dim3(64, 64),  256, 0, stream>>>(W1, w1t, 2048, 2048);       // W1T [2048][2048]
  // ns0 = xhi@whi + xhi@wlo + xlo@whi in one kernel (fp32 accumulate, fixed order)
  k1_fused  <<<dim3(4, 32),   256, 0, stream>>>(xhi, xlo, whi, wlo, ns0);
  k2_sim    <<<dim3(BH/256),  256, 0, stream>>>(ns0, out, zb);
  if (useCb) {
    k3_gemm<1><<<dim3((M3/256)*(Hdim/256)), 512, 0, stream>>>(zb, w1t, out + OUT_MEM, cbuf);
    k4_rec_cb<<<dim3(BH/256), 256, 0, stream>>>(cbuf, out);
  } else {
    k3_gemm<0><<<dim3((M3/256)*(Hdim/256)), 512, 0, stream>>>(zb, w1t, out + OUT_MEM, cbuf);
    k4_rec  <<<dim3(BH/256),  256, 0, stream>>>(out);
  }
}